// Round 6
// baseline (6639.777 us; speedup 1.0000x reference)
//
#include <hip/hip_runtime.h>
#include <math.h>

// ---------------------------------------------------------------------------
// Faster-RCNN forward, fp32. Round 6: conv_deep for c3/c4/c5 (stride-2 deep
// convs). Wave = one output channel (broadcast weight reads), lane = one
// spatial point (bank-spread patch reads), co split 4/block so grids are
// 2048-8192 blocks (was 512-1024 -> 24-50% occupancy). Per-output summation
// order unchanged (bias-first, ci->kh->kw) -> selection path bit-stable.
// Rest identical to verified round 5 (absmax 0.0).
// ---------------------------------------------------------------------------

#define NSEL 3768
#define MWORDS 60  // u64 words per mask row (59 needed, padded)

__device__ __forceinline__ unsigned key32(float f) {
  unsigned u = __float_as_uint(f);
  return (u & 0x80000000u) ? ~u : (u | 0x80000000u);
}

// ---------------------------------------------------------------------------
// Tiled direct conv (round-2 design, kept for stem/c2/1x1/fpn/rpn).
// ---------------------------------------------------------------------------
template<int K, int STRIDE, int TW, int TH, int BK, int PADLO, int MCO>
__global__ __launch_bounds__(256) void conv_tile(
    const float* __restrict__ in, const float* __restrict__ wgt,
    const float* __restrict__ bias, float* __restrict__ out,
    int Cin, int Hin, int Win, int Hout, int Wout, int do_relu,
    const float* __restrict__ up)
{
  constexpr int CO  = 16 * MCO;
  constexpr int PC  = TW * STRIDE + (K - STRIDE);
  constexpr int PR  = TH * STRIDE + (K - STRIDE);
  constexpr int PCP = (PC + 3) & ~3;
  constexpr int KK  = K * K;
  constexpr int SEG = 4 * STRIDE + (K - STRIDE);
  constexpr int PTOT = BK * PR * PCP;

  __shared__ __align__(16) float patch[BK][PR][PCP];
  __shared__ __align__(16) float wlds[BK][KK][CO];

  const int tid = threadIdx.x;
  const int tx = tid & 15, ty = tid >> 4;
  const int tilesW = Wout / TW;
  const int tw = blockIdx.x % tilesW, th = blockIdx.x / tilesW;
  const int OW0 = tw * TW, OH0 = th * TH;
  const int co_base = blockIdx.y * CO;
  const int sp0 = tx * 4;
  const int ow0 = sp0 % TW, oh0 = sp0 / TW;
  const int IW0 = OW0 * STRIDE - PADLO;
  const int IH0 = OH0 * STRIDE - PADLO;

  float acc[MCO][4];
#pragma unroll
  for (int i = 0; i < MCO; ++i) {
    float bv = bias[co_base + ty * MCO + i];
#pragma unroll
    for (int j = 0; j < 4; ++j) acc[i][j] = bv;
  }

  const int nk = Cin / BK;
  for (int ks = 0; ks < nk; ++ks) {
    const int cib = ks * BK;
    for (int e = tid; e < PTOT; e += 256) {
      int ci = e / (PR * PCP);
      int r  = (e / PCP) % PR;
      int pc = e % PCP;
      int gy = IH0 + r, gx = IW0 + pc;
      float v = 0.0f;
      if (pc < PC && (unsigned)gy < (unsigned)Hin && (unsigned)gx < (unsigned)Win)
        v = in[((size_t)(cib + ci) * Hin + gy) * Win + gx];
      ((float*)patch)[e] = v;
    }
    for (int p = tid; p < BK * CO; p += 256) {
      int co = p % CO, ci = p / CO;
      const float* wp = wgt + ((size_t)(co_base + co) * Cin + (cib + ci)) * KK;
#pragma unroll
      for (int k = 0; k < KK; ++k) wlds[ci][k][co] = wp[k];
    }
    __syncthreads();

#pragma unroll
    for (int ci = 0; ci < BK; ++ci) {
#pragma unroll
      for (int kh = 0; kh < K; ++kh) {
        float bseg[SEG];
        const float* bp = &patch[ci][oh0 * STRIDE + kh][ow0 * STRIDE];
        if constexpr (SEG == 4) {
          float4 t = *reinterpret_cast<const float4*>(bp);
          bseg[0] = t.x; bseg[1] = t.y; bseg[2] = t.z; bseg[3] = t.w;
        } else if constexpr (SEG == 6) {
          float4 t = *reinterpret_cast<const float4*>(bp);
          float2 u = *reinterpret_cast<const float2*>(bp + 4);
          bseg[0] = t.x; bseg[1] = t.y; bseg[2] = t.z; bseg[3] = t.w;
          bseg[4] = u.x; bseg[5] = u.y;
        } else if constexpr (SEG == 9) {
          float4 t = *reinterpret_cast<const float4*>(bp);
          float4 u = *reinterpret_cast<const float4*>(bp + 4);
          bseg[0] = t.x; bseg[1] = t.y; bseg[2] = t.z; bseg[3] = t.w;
          bseg[4] = u.x; bseg[5] = u.y; bseg[6] = u.z; bseg[7] = u.w;
          bseg[8] = bp[8];
        } else if constexpr (SEG == 13) {
          float4 t = *reinterpret_cast<const float4*>(bp);
          float4 u = *reinterpret_cast<const float4*>(bp + 4);
          float4 v = *reinterpret_cast<const float4*>(bp + 8);
          bseg[0] = t.x; bseg[1] = t.y; bseg[2] = t.z; bseg[3] = t.w;
          bseg[4] = u.x; bseg[5] = u.y; bseg[6] = u.z; bseg[7] = u.w;
          bseg[8] = v.x; bseg[9] = v.y; bseg[10] = v.z; bseg[11] = v.w;
          bseg[12] = bp[12];
        }
#pragma unroll
        for (int kw = 0; kw < K; ++kw) {
          float a[MCO];
          if constexpr (MCO == 4) {
            float4 av = *reinterpret_cast<const float4*>(&wlds[ci][kh * K + kw][ty * 4]);
            a[0] = av.x; a[1] = av.y; a[2] = av.z; a[3] = av.w;
          } else {
            a[0] = wlds[ci][kh * K + kw][ty];
          }
#pragma unroll
          for (int j = 0; j < 4; ++j) {
            float b = bseg[j * STRIDE + kw];
#pragma unroll
            for (int i = 0; i < MCO; ++i)
              acc[i][j] = fmaf(a[i], b, acc[i][j]);
          }
        }
      }
    }
    __syncthreads();
  }

  const int oh = OH0 + oh0;
#pragma unroll
  for (int i = 0; i < MCO; ++i) {
    int co = co_base + ty * MCO + i;
#pragma unroll
    for (int j = 0; j < 4; ++j) {
      int ow = OW0 + ow0 + j;
      float v = acc[i][j];
      if (up) {
        int H2 = Hout >> 1, W2 = Wout >> 1;
        v += up[((size_t)co * H2 + (oh >> 1)) * W2 + (ow >> 1)];
      }
      if (do_relu) v = fmaxf(v, 0.0f);
      out[((size_t)co * Hout + oh) * Wout + ow] = v;
    }
  }
}

// ---------------------------------------------------------------------------
// Deep stride-2 3x3 conv (c3/c4/c5): block = 4 waves x 64 lanes.
// wave w -> output channel co_base+w (weight reads wave-uniform broadcast),
// lane -> one spatial point of a 16x4 tile (patch reads bank-spread).
// Per-output accumulation order: bias, then ci asc -> kh asc -> kw asc
// (bit-identical to conv_tile). Pad = SAME hi-pad 1 via bounds check.
// ---------------------------------------------------------------------------
template<int BK>
__global__ __launch_bounds__(256) void conv_deep(
    const float* __restrict__ in, const float* __restrict__ wgt,
    const float* __restrict__ bias, float* __restrict__ out,
    int Cin, int Hin, int Win, int Hout, int Wout)
{
  constexpr int TW = 16, TH = 4;
  constexpr int PR = TH * 2 + 1;          // 9
  constexpr int PC = TW * 2 + 1;          // 33
  constexpr int PCP = (PC + 3) & ~3;      // 36
  constexpr int PTOT = BK * PR * PCP;

  __shared__ __align__(16) float patch[BK][PR][PCP];
  __shared__ float wlds[4][BK][9];

  const int tid = threadIdx.x;
  const int lane = tid & 63, w = tid >> 6;
  const int ow = lane & 15, oh = lane >> 4;
  const int tilesW = Wout / TW;
  const int tw = blockIdx.x % tilesW, th = blockIdx.x / tilesW;
  const int OW0 = tw * TW, OH0 = th * TH;
  const int co = blockIdx.y * 4 + w;
  const int IW0 = OW0 * 2, IH0 = OH0 * 2;

  float acc = bias[co];

  const int nk = Cin / BK;
  for (int ks = 0; ks < nk; ++ks) {
    const int cib = ks * BK;
    // stage input patch (zero hi-pad via bounds check)
    for (int e = tid; e < PTOT; e += 256) {
      int ci = e / (PR * PCP);
      int r  = (e / PCP) % PR;
      int pc = e % PCP;
      int gy = IH0 + r, gx = IW0 + pc;
      float v = 0.0f;
      if (pc < PC && gy < Hin && gx < Win)
        v = in[((size_t)(cib + ci) * Hin + gy) * Win + gx];
      ((float*)patch)[e] = v;
    }
    // stage weights [wave][ci][k]
    for (int p = tid; p < 4 * BK * 9; p += 256) {
      int ww = p / (BK * 9), rem = p % (BK * 9);
      int ci = rem / 9, k = rem % 9;
      wlds[ww][ci][k] =
          wgt[((size_t)(blockIdx.y * 4 + ww) * Cin + cib + ci) * 9 + k];
    }
    __syncthreads();

#pragma unroll
    for (int ci = 0; ci < BK; ++ci) {
#pragma unroll
      for (int kh = 0; kh < 3; ++kh) {
        const float* row = &patch[ci][oh * 2 + kh][ow * 2];
        float2 v01 = *reinterpret_cast<const float2*>(row);
        float v2 = row[2];
        acc = fmaf(v01.x, wlds[w][ci][kh * 3 + 0], acc);
        acc = fmaf(v01.y, wlds[w][ci][kh * 3 + 1], acc);
        acc = fmaf(v2,    wlds[w][ci][kh * 3 + 2], acc);
      }
    }
    __syncthreads();
  }

  acc = fmaxf(acc, 0.0f);  // c3/c4/c5 all have relu
  out[((size_t)co * Hout + OH0 + oh) * Wout + OW0 + ow] = acc;
}

// ---------------- maxpool 3x3 s2 SAME: 64x256x256 -> 64x128x128 ------------
__global__ __launch_bounds__(256) void maxpool_kernel(
    const float* __restrict__ in, float* __restrict__ out)
{
  int c = blockIdx.z;
  int w = blockIdx.x * 16 + threadIdx.x;
  int h = blockIdx.y * 16 + threadIdx.y;
  if (w >= 128 || h >= 128) return;
  const float* p = in + (size_t)c * 256 * 256;
  float m = -INFINITY;
  for (int kh = 0; kh < 3; ++kh) {
    int hi = h * 2 + kh;
    if (hi < 256)
      for (int kw = 0; kw < 3; ++kw) {
        int wi = w * 2 + kw;
        if (wi < 256) m = fmaxf(m, p[hi * 256 + wi]);
      }
  }
  out[((size_t)c * 128 + h) * 128 + w] = m;
}

// ---------------- RPN head: cls/reg 1x1 conv + anchor decode ---------------
__global__ __launch_bounds__(256) void rpn_head_kernel(
    const float* __restrict__ t,
    const float* __restrict__ clsw, const float* __restrict__ clsb,
    const float* __restrict__ regw, const float* __restrict__ regb,
    float* __restrict__ scores, float* __restrict__ boxes,
    int H, int W, int stride, float asize, int base)
{
  int idx = blockIdx.x * blockDim.x + threadIdx.x;
  int n = H * W * 3;
  if (idx >= n) return;
  int a = idx % 3;
  int pos = idx / 3;
  int wp = pos % W, hp = pos / W;
  size_t hw = (size_t)H * W;
  const float* tp = t + (size_t)hp * W + wp;
  const float* cw = clsw + a * 256;
  const float* rw0 = regw + (a * 4 + 0) * 256;
  const float* rw1 = regw + (a * 4 + 1) * 256;
  const float* rw2 = regw + (a * 4 + 2) * 256;
  const float* rw3 = regw + (a * 4 + 3) * 256;
  float s = clsb[a];
  float d0 = regb[a * 4 + 0], d1 = regb[a * 4 + 1];
  float d2 = regb[a * 4 + 2], d3 = regb[a * 4 + 3];
  for (int c = 0; c < 256; ++c) {
    float v = tp[c * hw];
    s = fmaf(v, cw[c], s);
    d0 = fmaf(v, rw0[c], d0);
    d1 = fmaf(v, rw1[c], d1);
    d2 = fmaf(v, rw2[c], d2);
    d3 = fmaf(v, rw3[c], d3);
  }
  float r = (a == 0) ? 0.5f : ((a == 1) ? 1.0f : 2.0f);
  float hr = sqrtf(r);
  float ws = asize / hr, hs = asize * hr;
  float cx0 = ((float)wp + 0.5f) * (float)stride;
  float cy0 = ((float)hp + 0.5f) * (float)stride;
  float ax1 = cx0 - ws * 0.5f, ax2 = cx0 + ws * 0.5f;
  float ay1 = cy0 - hs * 0.5f, ay2 = cy0 + hs * 0.5f;
  float aw = ax2 - ax1, ah = ay2 - ay1;
  float acx = ax1 + aw * 0.5f, acy = ay1 + ah * 0.5f;
  float dw = fminf(fmaxf(d2, -4.135f), 4.135f);
  float dh = fminf(fmaxf(d3, -4.135f), 4.135f);
  float cx = d0 * aw + acx;
  float cy = d1 * ah + acy;
  float bw = aw * expf(dw);
  float bh = ah * expf(dh);
  float x1 = fminf(fmaxf(cx - bw * 0.5f, 0.0f), 512.0f);
  float y1 = fminf(fmaxf(cy - bh * 0.5f, 0.0f), 512.0f);
  float x2 = fminf(fmaxf(cx + bw * 0.5f, 0.0f), 512.0f);
  float y2 = fminf(fmaxf(cy + bh * 0.5f, 0.0f), 512.0f);
  scores[base + idx] = s;
  float* bp = boxes + 4 * (size_t)(base + idx);
  bp[0] = x1; bp[1] = y1; bp[2] = x2; bp[3] = y2;
}

// ---------------- per-level exact top-k via radix select -------------------
__global__ __launch_bounds__(256) void topk_kernel(
    const float* __restrict__ scores_all, const float* __restrict__ boxes_all,
    float* __restrict__ sel_s, float* __restrict__ sel_b)
{
  const int offs[5] = {0, 49152, 61440, 64512, 65280};
  const int kks[4]  = {1000, 1000, 1000, 768};
  const int soff[4] = {0, 1000, 2000, 3000};
  int l = blockIdx.x;
  int lo = offs[l], n = offs[l + 1] - lo, k = kks[l], so = soff[l];
  int tid = threadIdx.x;

  if (k >= n) {
    for (int i = tid; i < n; i += blockDim.x) {
      sel_s[so + i] = scores_all[lo + i];
      const float* bp = boxes_all + 4 * (size_t)(lo + i);
      float* op = sel_b + 4 * (size_t)(so + i);
      op[0] = bp[0]; op[1] = bp[1]; op[2] = bp[2]; op[3] = bp[3];
    }
    return;
  }

  __shared__ unsigned hist[256];
  __shared__ unsigned sh_prefix, sh_mask;
  __shared__ int sh_k, cnt1, cnt2;
  if (tid == 0) { sh_prefix = 0u; sh_mask = 0u; sh_k = k; cnt1 = 0; cnt2 = 0; }
  __syncthreads();

  for (int p = 3; p >= 0; --p) {
    hist[tid] = 0u;
    __syncthreads();
    unsigned pre = sh_prefix, msk = sh_mask;
    for (int i = tid; i < n; i += blockDim.x) {
      unsigned u = key32(scores_all[lo + i]);
      if ((u & msk) == pre)
        atomicAdd(&hist[(u >> (p * 8)) & 255u], 1u);
    }
    __syncthreads();
    if (tid == 0) {
      int rem = sh_k, b;
      for (b = 255; b >= 0; --b) {
        int c = (int)hist[b];
        if (rem <= c) break;
        rem -= c;
      }
      if (b < 0) b = 0;
      sh_k = rem;
      sh_prefix |= ((unsigned)b << (p * 8));
      sh_mask |= (255u << (p * 8));
    }
    __syncthreads();
  }
  unsigned T = sh_prefix;

  for (int i = tid; i < n; i += blockDim.x) {
    float sc = scores_all[lo + i];
    if (key32(sc) > T) {
      int pos = atomicAdd(&cnt1, 1);
      sel_s[so + pos] = sc;
      const float* bp = boxes_all + 4 * (size_t)(lo + i);
      float* op = sel_b + 4 * (size_t)(so + pos);
      op[0] = bp[0]; op[1] = bp[1]; op[2] = bp[2]; op[3] = bp[3];
    }
  }
  __syncthreads();
  int ngreater = cnt1;
  for (int i = tid; i < n; i += blockDim.x) {
    float sc = scores_all[lo + i];
    if (key32(sc) == T) {
      int pos = atomicAdd(&cnt2, 1);
      if (ngreater + pos < k) {
        sel_s[so + ngreater + pos] = sc;
        const float* bp = boxes_all + 4 * (size_t)(lo + i);
        float* op = sel_b + 4 * (size_t)(so + ngreater + pos);
        op[0] = bp[0]; op[1] = bp[1]; op[2] = bp[2]; op[3] = bp[3];
      }
    }
  }
}

// ---------------- NMS part (a): parallel IoU suppression bitmask -----------
__global__ __launch_bounds__(256) void nms_mask_kernel(
    const float* __restrict__ sel_b, unsigned long long* __restrict__ mask)
{
  int wid = (blockIdx.x * 256 + threadIdx.x) >> 6;
  int lane = threadIdx.x & 63;
  if (wid >= NSEL) return;
  const float* bb = sel_b + 4 * (size_t)wid;
  float bx1 = bb[0], by1 = bb[1], bx2 = bb[2], by2 = bb[3];
  float barea = (bx2 - bx1) * (by2 - by1);
  unsigned long long* row = mask + (size_t)wid * MWORDS;
  for (int w = 0; w < MWORDS; ++w) {
    int j = w * 64 + lane;
    bool sup = false;
    if (j < NSEL) {
      const float* pB = sel_b + 4 * (size_t)j;
      float px1 = pB[0], py1 = pB[1], px2 = pB[2], py2 = pB[3];
      float ix1 = fmaxf(bx1, px1), iy1 = fmaxf(by1, py1);
      float ix2 = fminf(bx2, px2), iy2 = fminf(by2, py2);
      float inter = fmaxf(ix2 - ix1, 0.0f) * fmaxf(iy2 - iy1, 0.0f);
      float areab = (px2 - px1) * (py2 - py1);
      float iou = inter / fmaxf(barea + areab - inter, 1e-6f);
      sup = iou > 0.7f;
    }
    unsigned long long bal = __ballot(sup);
    if (lane == 0) row[w] = bal;
  }
}

// ---------------- NMS part (b): sequential argmax + mask suppress ----------
__global__ __launch_bounds__(512) void nms_seq_kernel(
    const float* __restrict__ sel_s, const float* __restrict__ sel_b,
    const unsigned long long* __restrict__ mask, float* __restrict__ props)
{
  __shared__ float s[NSEL];
  __shared__ float wv[8];
  __shared__ int wi[8];
  __shared__ int cur;
  int tid = threadIdx.x;
  for (int i = tid; i < NSEL; i += 512) s[i] = sel_s[i];
  __syncthreads();

  for (int it = 0; it < 300; ++it) {
    float bv = -INFINITY;
    int bi = 0x7fffffff;
#pragma unroll
    for (int k = 0; k < 8; ++k) {
      int e = tid + k * 512;
      if (e < NSEL) {
        float v = s[e];
        if (v > bv || (v == bv && e < bi)) { bv = v; bi = e; }
      }
    }
    for (int off = 32; off >= 1; off >>= 1) {
      float ov = __shfl_down(bv, off);
      int oi = __shfl_down(bi, off);
      if (ov > bv || (ov == bv && oi < bi)) { bv = ov; bi = oi; }
    }
    int wave = tid >> 6;
    if ((tid & 63) == 0) { wv[wave] = bv; wi[wave] = bi; }
    __syncthreads();
    if (tid == 0) {
      float v0 = wv[0]; int i0 = wi[0];
      for (int q = 1; q < 8; ++q)
        if (wv[q] > v0 || (wv[q] == v0 && wi[q] < i0)) { v0 = wv[q]; i0 = wi[q]; }
      cur = i0;
    }
    __syncthreads();
    int c = cur;
    if (tid < 4) props[it * 4 + tid] = sel_b[4 * (size_t)c + tid];
    const unsigned long long* row = mask + (size_t)c * MWORDS;
#pragma unroll
    for (int k = 0; k < 8; ++k) {
      int e = tid + k * 512;
      if (e < NSEL) {
        if ((row[e >> 6] >> (e & 63)) & 1ull) s[e] = -INFINITY;
      }
    }
    __syncthreads();
  }
}

// ---------------- RoI align 7x7 (sr=2), writes FC input rows ---------------
__global__ __launch_bounds__(256) void roi_align_kernel(
    const float* __restrict__ props,
    const float* __restrict__ f2, const float* __restrict__ f3,
    const float* __restrict__ f4, const float* __restrict__ f5,
    float* __restrict__ fcin)
{
  int r = blockIdx.x;
  const float* bp = props + 4 * (size_t)r;
  float x1 = bp[0], y1 = bp[1], x2 = bp[2], y2 = bp[3];
  float area = fmaxf((x2 - x1) * (y2 - y1), 1e-6f);
  float lf = floorf(4.0f + log2f(sqrtf(area) / 224.0f));
  lf = fminf(fmaxf(lf, 2.0f), 5.0f);
  int lvl = (int)lf - 2;
  const float* feat; int H; float scale;
  if (lvl == 0)      { feat = f2; H = 128; scale = 0.25f; }
  else if (lvl == 1) { feat = f3; H = 64;  scale = 0.125f; }
  else if (lvl == 2) { feat = f4; H = 32;  scale = 0.0625f; }
  else               { feat = f5; H = 16;  scale = 0.03125f; }
  int W = H;

  __shared__ int   sy0[14], sy1[14], sx0[14], sx1[14];
  __shared__ float swy0[14], swy1[14], swx0[14], swx1[14];
  int tid = threadIdx.x;
  if (tid < 28) {
    int j = tid % 14;
    bool isx = tid >= 14;
    float b1 = (isx ? x1 : y1) * scale;
    float b2 = (isx ? x2 : y2) * scale;
    float bs = fmaxf(b2 - b1, 1.0f) * (1.0f / 7.0f);
    float g = (float)(j >> 1) + ((j & 1) ? 0.75f : 0.25f);
    float coord = b1 + g * bs;
    coord = fminf(fmaxf(coord, 0.0f), (float)(H - 1));
    int c0 = (int)floorf(coord);
    int c1 = min(c0 + 1, H - 1);
    float w1 = coord - (float)c0;
    if (isx) { sx0[j] = c0; sx1[j] = c1; swx1[j] = w1; swx0[j] = 1.0f - w1; }
    else     { sy0[j] = c0; sy1[j] = c1; swy1[j] = w1; swy0[j] = 1.0f - w1; }
  }
  __syncthreads();

  int c = tid;
  const float* fp = feat + (size_t)c * H * W;
  float* op = fcin + (size_t)r * 12544 + (size_t)c * 49;
  for (int oh = 0; oh < 7; ++oh) {
    for (int ow = 0; ow < 7; ++ow) {
      float acc = 0.0f;
#pragma unroll
      for (int sy = 0; sy < 2; ++sy) {
        int i = oh * 2 + sy;
        int yy0 = sy0[i], yy1 = sy1[i];
        float wy0 = swy0[i], wy1 = swy1[i];
#pragma unroll
        for (int sx = 0; sx < 2; ++sx) {
          int j = ow * 2 + sx;
          int xx0 = sx0[j], xx1 = sx1[j];
          float wx0 = swx0[j], wx1 = swx1[j];
          float v = wy0 * wx0 * fp[yy0 * W + xx0]
                  + wy0 * wx1 * fp[yy0 * W + xx1]
                  + wy1 * wx0 * fp[yy1 * W + xx0]
                  + wy1 * wx1 * fp[yy1 * W + xx1];
          acc += v;
        }
      }
      op[oh * 7 + ow] = acc * 0.25f;
    }
  }
}

// ---------------- split-K GEMM: part[kc] += A[M,K] * B[N,K]^T --------------
__global__ __launch_bounds__(256) void gemm_splitk(
    const float* __restrict__ A, const float* __restrict__ B,
    float* __restrict__ part, int M, int N, int K, int klen)
{
  __shared__ float As[16][66];
  __shared__ float Bs[16][66];
  int tid = threadIdx.x;
  int tx = tid % 16, ty = tid / 16;
  int m0 = blockIdx.y * 64, n0 = blockIdx.x * 64;
  int kc = blockIdx.z;
  int kt0 = kc * klen, kt1 = kt0 + klen;
  float acc[4][4] = {};
  for (int kt = kt0; kt < kt1; kt += 16) {
#pragma unroll
    for (int i = 0; i < 4; ++i) {
      int flat = tid + 256 * i;
      int mm = flat >> 4, kk = flat & 15;
      int m = m0 + mm;
      As[kk][mm] = (m < M) ? A[(size_t)m * K + kt + kk] : 0.0f;
      int nn = n0 + mm;
      Bs[kk][mm] = (nn < N) ? B[(size_t)nn * K + kt + kk] : 0.0f;
    }
    __syncthreads();
#pragma unroll
    for (int kk = 0; kk < 16; ++kk) {
      float av[4], bv[4];
#pragma unroll
      for (int i = 0; i < 4; ++i) av[i] = As[kk][ty * 4 + i];
#pragma unroll
      for (int j = 0; j < 4; ++j) bv[j] = Bs[kk][tx * 4 + j];
#pragma unroll
      for (int i = 0; i < 4; ++i)
#pragma unroll
        for (int j = 0; j < 4; ++j)
          acc[i][j] = fmaf(av[i], bv[j], acc[i][j]);
    }
    __syncthreads();
  }
  float* pslab = part + (size_t)kc * M * N;
#pragma unroll
  for (int i = 0; i < 4; ++i) {
    int m = m0 + ty * 4 + i;
    if (m >= M) continue;
#pragma unroll
    for (int j = 0; j < 4; ++j) {
      int n = n0 + tx * 4 + j;
      if (n >= N) continue;
      pslab[(size_t)m * N + n] = acc[i][j];
    }
  }
}

// ---------------- reduce partials + bias + relu ----------------------------
__global__ __launch_bounds__(256) void reduce_bias_relu(
    const float* __restrict__ part, int nchunk,
    const float* __restrict__ bias, float* __restrict__ C,
    int MN, int N, int do_relu)
{
  int idx = blockIdx.x * 256 + threadIdx.x;
  if (idx >= MN) return;
  float v = bias[idx % N];
  for (int c = 0; c < nchunk; ++c) v += part[(size_t)c * MN + idx];
  if (do_relu) v = fmaxf(v, 0.0f);
  C[idx] = v;
}

// ---------------- cls/reg heads: out[300][60] ------------------------------
__global__ __launch_bounds__(256) void heads_kernel(
    const float* __restrict__ h,
    const float* __restrict__ clsw, const float* __restrict__ clsb,
    const float* __restrict__ regw, const float* __restrict__ regb,
    float* __restrict__ out)
{
  int idx = blockIdx.x * blockDim.x + threadIdx.x;
  if (idx >= 300 * 60) return;
  int r = idx / 60, o = idx % 60;
  const float* wrow = (o < 12) ? (clsw + (size_t)o * 1024)
                               : (regw + (size_t)(o - 12) * 1024);
  float acc = (o < 12) ? clsb[o] : regb[o - 12];
  const float* hr = h + (size_t)r * 1024;
  for (int k = 0; k < 1024; ++k) acc = fmaf(hr[k], wrow[k], acc);
  out[idx] = acc;
}

// ---------------------------------------------------------------------------
extern "C" void kernel_launch(void* const* d_in, const int* in_sizes, int n_in,
                              void* d_out, int out_size, void* d_ws, size_t ws_size,
                              hipStream_t stream) {
  const float* images  = (const float*)d_in[0];
  const float* stem_w  = (const float*)d_in[1];
  const float* stem_b  = (const float*)d_in[2];
  const float* c2_w    = (const float*)d_in[3];
  const float* c2_b    = (const float*)d_in[4];
  const float* c3_w    = (const float*)d_in[5];
  const float* c3_b    = (const float*)d_in[6];
  const float* c4_w    = (const float*)d_in[7];
  const float* c4_b    = (const float*)d_in[8];
  const float* c5_w    = (const float*)d_in[9];
  const float* c5_b    = (const float*)d_in[10];
  const float* lat2_w  = (const float*)d_in[11];
  const float* lat2_b  = (const float*)d_in[12];
  const float* lat3_w  = (const float*)d_in[13];
  const float* lat3_b  = (const float*)d_in[14];
  const float* lat4_w  = (const float*)d_in[15];
  const float* lat4_b  = (const float*)d_in[16];
  const float* lat5_w  = (const float*)d_in[17];
  const float* lat5_b  = (const float*)d_in[18];
  const float* fpn2_w  = (const float*)d_in[19];
  const float* fpn2_b  = (const float*)d_in[20];
  const float* fpn3_w  = (const float*)d_in[21];
  const float* fpn3_b  = (const float*)d_in[22];
  const float* fpn4_w  = (const float*)d_in[23];
  const float* fpn4_b  = (const float*)d_in[24];
  const float* fpn5_w  = (const float*)d_in[25];
  const float* fpn5_b  = (const float*)d_in[26];
  const float* rpn_w   = (const float*)d_in[27];
  const float* rpn_b   = (const float*)d_in[28];
  const float* rpncls_w = (const float*)d_in[29];
  const float* rpncls_b = (const float*)d_in[30];
  const float* rpnreg_w = (const float*)d_in[31];
  const float* rpnreg_b = (const float*)d_in[32];
  const float* fc1_w   = (const float*)d_in[33];
  const float* fc1_b   = (const float*)d_in[34];
  const float* fc2_w   = (const float*)d_in[35];
  const float* fc2_b   = (const float*)d_in[36];
  const float* cls_w   = (const float*)d_in[37];
  const float* cls_b   = (const float*)d_in[38];
  const float* reg_w   = (const float*)d_in[39];
  const float* reg_b   = (const float*)d_in[40];

  const size_t NEED = 18677760ull * 4ull;
  if (ws_size < NEED) return;
  float* ws = (float*)d_ws;
  float* STEM = ws;                       // 4,194,304  (later: FCIN 3,763,200)
  float* POOL = ws + 4194304;             // 1,048,576  (later: small buffers)
  float* C2   = ws + 5242880;             // 4,194,304  (later: fpn p2; then fc1 partials)
  float* C3   = ws + 9437184;             // 2,097,152  (later: fpn p3; then fc2 partials)
  float* C4   = ws + 11534336;            // 1,048,576  (later: fpn p4)
  float* C5   = ws + 12582912;            //   524,288  (later: fpn p5)
  float* LAT2 = ws + 13107200;            // 4,194,304  (later: RPN t; then NMS masks)
  float* LAT3 = ws + 17301504;            // 1,048,576
  float* LAT4 = ws + 18350080;            //   262,144
  float* LAT5 = ws + 18612224;            //    65,536
  float* SCORES = POOL;                   // 65,280
  float* BOXES  = POOL + 65280;           // 261,120
  float* SELS   = POOL + 326400;          // 3,768
  float* SELB   = POOL + 330168;          // 15,072
  float* PROPS  = POOL + 345240;          // 1,200
  float* FC1O   = POOL + 346440;          // 307,200
  float* FC2O   = POOL + 653640;          // 307,200
  float* FCIN = STEM;
  float* RPNT = LAT2;
  float* PART1 = C2;                      // 8*300*1024 = 2,457,600 <= 4,194,304
  float* PART2 = C3;                      // 4*300*1024 = 1,228,800 <= 2,097,152
  unsigned long long* MASKS = (unsigned long long*)RPNT;

  dim3 b16(16, 16);

  // backbone
  conv_tile<7,2,16,4,3,2,4><<<dim3(1024, 1), 256, 0, stream>>>(
      images, stem_w, stem_b, STEM, 3, 512, 512, 256, 256, 1, nullptr);
  maxpool_kernel<<<dim3(8, 8, 64), b16, 0, stream>>>(STEM, POOL);
  conv_tile<3,1,64,1,8,1,4><<<dim3(256, 4), 256, 0, stream>>>(
      POOL, c2_w, c2_b, C2, 64, 128, 128, 128, 128, 1, nullptr);
  // deep stride-2 convs: wave-per-co layout, high-occupancy grids
  conv_deep<8><<<dim3(64, 128), 256, 0, stream>>>(
      C2, c3_w, c3_b, C3, 256, 128, 128, 64, 64);
  conv_deep<8><<<dim3(16, 256), 256, 0, stream>>>(
      C3, c4_w, c4_b, C4, 512, 64, 64, 32, 32);
  conv_deep<8><<<dim3(4, 512), 256, 0, stream>>>(
      C4, c5_w, c5_b, C5, 1024, 32, 32, 16, 16);

  // FPN laterals (1x1, top-down with fused up2 add)
  conv_tile<1,1,16,4,8,0,4><<<dim3(4, 4), 256, 0, stream>>>(
      C5, lat5_w, lat5_b, LAT5, 2048, 16, 16, 16, 16, 0, nullptr);
  conv_tile<1,1,32,2,8,0,4><<<dim3(16, 4), 256, 0, stream>>>(
      C4, lat4_w, lat4_b, LAT4, 1024, 32, 32, 32, 32, 0, LAT5);
  conv_tile<1,1,64,1,8,0,4><<<dim3(64, 4), 256, 0, stream>>>(
      C3, lat3_w, lat3_b, LAT3, 512, 64, 64, 64, 64, 0, LAT4);
  conv_tile<1,1,64,1,8,0,4><<<dim3(256, 4), 256, 0, stream>>>(
      C2, lat2_w, lat2_b, LAT2, 256, 128, 128, 128, 128, 0, LAT3);

  // FPN 3x3 smoothing (outputs overwrite dead C2..C5)
  conv_tile<3,1,64,1,8,1,4><<<dim3(256, 4), 256, 0, stream>>>(
      LAT2, fpn2_w, fpn2_b, C2, 256, 128, 128, 128, 128, 0, nullptr);
  conv_tile<3,1,64,1,8,1,4><<<dim3(64, 4), 256, 0, stream>>>(
      LAT3, fpn3_w, fpn3_b, C3, 256, 64, 64, 64, 64, 0, nullptr);
  conv_tile<3,1,32,2,8,1,4><<<dim3(16, 4), 256, 0, stream>>>(
      LAT4, fpn4_w, fpn4_b, C4, 256, 32, 32, 32, 32, 0, nullptr);
  conv_tile<3,1,16,4,8,1,4><<<dim3(4, 4), 256, 0, stream>>>(
      LAT5, fpn5_w, fpn5_b, C5, 256, 16, 16, 16, 16, 0, nullptr);

  // RPN per level
  conv_tile<3,1,64,1,8,1,4><<<dim3(256, 4), 256, 0, stream>>>(
      C2, rpn_w, rpn_b, RPNT, 256, 128, 128, 128, 128, 1, nullptr);
  rpn_head_kernel<<<(49152 + 255) / 256, 256, 0, stream>>>(
      RPNT, rpncls_w, rpncls_b, rpnreg_w, rpnreg_b, SCORES, BOXES,
      128, 128, 4, 32.0f, 0);
  conv_tile<3,1,64,1,8,1,4><<<dim3(64, 4), 256, 0, stream>>>(
      C3, rpn_w, rpn_b, RPNT, 256, 64, 64, 64, 64, 1, nullptr);
  rpn_head_kernel<<<(12288 + 255) / 256, 256, 0, stream>>>(
      RPNT, rpncls_w, rpncls_b, rpnreg_w, rpnreg_b, SCORES, BOXES,
      64, 64, 8, 64.0f, 49152);
  conv_tile<3,1,32,2,8,1,4><<<dim3(16, 4), 256, 0, stream>>>(
      C4, rpn_w, rpn_b, RPNT, 256, 32, 32, 32, 32, 1, nullptr);
  rpn_head_kernel<<<(3072 + 255) / 256, 256, 0, stream>>>(
      RPNT, rpncls_w, rpncls_b, rpnreg_w, rpnreg_b, SCORES, BOXES,
      32, 32, 16, 128.0f, 61440);
  conv_tile<3,1,16,4,8,1,4><<<dim3(4, 4), 256, 0, stream>>>(
      C5, rpn_w, rpn_b, RPNT, 256, 16, 16, 16, 16, 1, nullptr);
  rpn_head_kernel<<<(768 + 255) / 256, 256, 0, stream>>>(
      RPNT, rpncls_w, rpncls_b, rpnreg_w, rpnreg_b, SCORES, BOXES,
      16, 16, 32, 256.0f, 64512);

  // selection: top-k -> parallel IoU masks -> lean sequential NMS
  topk_kernel<<<4, 256, 0, stream>>>(SCORES, BOXES, SELS, SELB);
  nms_mask_kernel<<<(NSEL * 64 + 255) / 256, 256, 0, stream>>>(SELB, MASKS);
  nms_seq_kernel<<<1, 512, 0, stream>>>(SELS, SELB, MASKS, PROPS);

  // RoI align into FC input rows (FCIN aliases dead STEM)
  roi_align_kernel<<<300, 256, 0, stream>>>(PROPS, C2, C3, C4, C5, FCIN);

  // FC head, split-K (PART1/PART2 alias C2/C3 which are dead after roi_align)
  gemm_splitk<<<dim3(16, 5, 8), 256, 0, stream>>>(
      FCIN, fc1_w, PART1, 300, 1024, 12544, 1568);
  reduce_bias_relu<<<(307200 + 255) / 256, 256, 0, stream>>>(
      PART1, 8, fc1_b, FC1O, 307200, 1024, 1);
  gemm_splitk<<<dim3(16, 5, 4), 256, 0, stream>>>(
      FC1O, fc2_w, PART2, 300, 1024, 1024, 256);
  reduce_bias_relu<<<(307200 + 255) / 256, 256, 0, stream>>>(
      PART2, 4, fc2_b, FC2O, 307200, 1024, 1);
  heads_kernel<<<(18000 + 255) / 256, 256, 0, stream>>>(
      FC2O, cls_w, cls_b, reg_w, reg_b, (float*)d_out);
}

// Round 7
// 4900.327 us; speedup vs baseline: 1.3550x; 1.3550x over previous
//
#include <hip/hip_runtime.h>
#include <math.h>

// ---------------------------------------------------------------------------
// Faster-RCNN forward, fp32. Round 7: conv_deep REVERTED (it regressed:
// VALUBusy 85% but all overhead). c3/c4/c5 now implicit-GEMM with split-K
// (M=Cout, N=spatial, K=Cin*9, on-the-fly im2col B tile, 4x4 register
// micro-tile) -> 1024 blocks each. Partials in dead LAT2 region; reduce
// applies bias+relu. K-order within chunk = ci->kh->kw ascending (unchanged);
// chunk/bias reassociation is the same transform as the verified FC split-K.
// Everything else identical to verified round 5 (absmax 0.0, 5836us).
// ---------------------------------------------------------------------------

#define NSEL 3768
#define MWORDS 60  // u64 words per mask row (59 needed, padded)

__device__ __forceinline__ unsigned key32(float f) {
  unsigned u = __float_as_uint(f);
  return (u & 0x80000000u) ? ~u : (u | 0x80000000u);
}

// ---------------------------------------------------------------------------
// Tiled direct conv (round-2 design: stem/c2/1x1-lat/fpn/rpn).
// ---------------------------------------------------------------------------
template<int K, int STRIDE, int TW, int TH, int BK, int PADLO, int MCO>
__global__ __launch_bounds__(256) void conv_tile(
    const float* __restrict__ in, const float* __restrict__ wgt,
    const float* __restrict__ bias, float* __restrict__ out,
    int Cin, int Hin, int Win, int Hout, int Wout, int do_relu,
    const float* __restrict__ up)
{
  constexpr int CO  = 16 * MCO;
  constexpr int PC  = TW * STRIDE + (K - STRIDE);
  constexpr int PR  = TH * STRIDE + (K - STRIDE);
  constexpr int PCP = (PC + 3) & ~3;
  constexpr int KK  = K * K;
  constexpr int SEG = 4 * STRIDE + (K - STRIDE);
  constexpr int PTOT = BK * PR * PCP;

  __shared__ __align__(16) float patch[BK][PR][PCP];
  __shared__ __align__(16) float wlds[BK][KK][CO];

  const int tid = threadIdx.x;
  const int tx = tid & 15, ty = tid >> 4;
  const int tilesW = Wout / TW;
  const int tw = blockIdx.x % tilesW, th = blockIdx.x / tilesW;
  const int OW0 = tw * TW, OH0 = th * TH;
  const int co_base = blockIdx.y * CO;
  const int sp0 = tx * 4;
  const int ow0 = sp0 % TW, oh0 = sp0 / TW;
  const int IW0 = OW0 * STRIDE - PADLO;
  const int IH0 = OH0 * STRIDE - PADLO;

  float acc[MCO][4];
#pragma unroll
  for (int i = 0; i < MCO; ++i) {
    float bv = bias[co_base + ty * MCO + i];
#pragma unroll
    for (int j = 0; j < 4; ++j) acc[i][j] = bv;
  }

  const int nk = Cin / BK;
  for (int ks = 0; ks < nk; ++ks) {
    const int cib = ks * BK;
    for (int e = tid; e < PTOT; e += 256) {
      int ci = e / (PR * PCP);
      int r  = (e / PCP) % PR;
      int pc = e % PCP;
      int gy = IH0 + r, gx = IW0 + pc;
      float v = 0.0f;
      if (pc < PC && (unsigned)gy < (unsigned)Hin && (unsigned)gx < (unsigned)Win)
        v = in[((size_t)(cib + ci) * Hin + gy) * Win + gx];
      ((float*)patch)[e] = v;
    }
    for (int p = tid; p < BK * CO; p += 256) {
      int co = p % CO, ci = p / CO;
      const float* wp = wgt + ((size_t)(co_base + co) * Cin + (cib + ci)) * KK;
#pragma unroll
      for (int k = 0; k < KK; ++k) wlds[ci][k][co] = wp[k];
    }
    __syncthreads();

#pragma unroll
    for (int ci = 0; ci < BK; ++ci) {
#pragma unroll
      for (int kh = 0; kh < K; ++kh) {
        float bseg[SEG];
        const float* bp = &patch[ci][oh0 * STRIDE + kh][ow0 * STRIDE];
        if constexpr (SEG == 4) {
          float4 t = *reinterpret_cast<const float4*>(bp);
          bseg[0] = t.x; bseg[1] = t.y; bseg[2] = t.z; bseg[3] = t.w;
        } else if constexpr (SEG == 6) {
          float4 t = *reinterpret_cast<const float4*>(bp);
          float2 u = *reinterpret_cast<const float2*>(bp + 4);
          bseg[0] = t.x; bseg[1] = t.y; bseg[2] = t.z; bseg[3] = t.w;
          bseg[4] = u.x; bseg[5] = u.y;
        } else if constexpr (SEG == 9) {
          float4 t = *reinterpret_cast<const float4*>(bp);
          float4 u = *reinterpret_cast<const float4*>(bp + 4);
          bseg[0] = t.x; bseg[1] = t.y; bseg[2] = t.z; bseg[3] = t.w;
          bseg[4] = u.x; bseg[5] = u.y; bseg[6] = u.z; bseg[7] = u.w;
          bseg[8] = bp[8];
        } else if constexpr (SEG == 13) {
          float4 t = *reinterpret_cast<const float4*>(bp);
          float4 u = *reinterpret_cast<const float4*>(bp + 4);
          float4 v = *reinterpret_cast<const float4*>(bp + 8);
          bseg[0] = t.x; bseg[1] = t.y; bseg[2] = t.z; bseg[3] = t.w;
          bseg[4] = u.x; bseg[5] = u.y; bseg[6] = u.z; bseg[7] = u.w;
          bseg[8] = v.x; bseg[9] = v.y; bseg[10] = v.z; bseg[11] = v.w;
          bseg[12] = bp[12];
        }
#pragma unroll
        for (int kw = 0; kw < K; ++kw) {
          float a[MCO];
          if constexpr (MCO == 4) {
            float4 av = *reinterpret_cast<const float4*>(&wlds[ci][kh * K + kw][ty * 4]);
            a[0] = av.x; a[1] = av.y; a[2] = av.z; a[3] = av.w;
          } else {
            a[0] = wlds[ci][kh * K + kw][ty];
          }
#pragma unroll
          for (int j = 0; j < 4; ++j) {
            float b = bseg[j * STRIDE + kw];
#pragma unroll
            for (int i = 0; i < MCO; ++i)
              acc[i][j] = fmaf(a[i], b, acc[i][j]);
          }
        }
      }
    }
    __syncthreads();
  }

  const int oh = OH0 + oh0;
#pragma unroll
  for (int i = 0; i < MCO; ++i) {
    int co = co_base + ty * MCO + i;
#pragma unroll
    for (int j = 0; j < 4; ++j) {
      int ow = OW0 + ow0 + j;
      float v = acc[i][j];
      if (up) {
        int H2 = Hout >> 1, W2 = Wout >> 1;
        v += up[((size_t)co * H2 + (oh >> 1)) * W2 + (ow >> 1)];
      }
      if (do_relu) v = fmaxf(v, 0.0f);
      out[((size_t)co * Hout + oh) * Wout + ow] = v;
    }
  }
}

// ---------------------------------------------------------------------------
// Implicit-GEMM stride-2 3x3 conv with split-K (c3/c4/c5).
// A = wgt [M][K] (K=Cin*9, row-major as stored), B = im2col [K][Nsp] built
// on the fly. Tile 64co x 64sp, 4x4 register micro-tile, K-step 16.
// grid = (Nsp/64, M/64, nchunk), kchunk multiple of 16.
// Within-chunk k order = ci->kh->kw ascending (matches direct conv).
// Writes partial slab part[kc][M*Nsp] (no bias).
// WSHIFT: log2(Wout). SAME pad for stride 2 = hi-pad only (bounds check).
// ---------------------------------------------------------------------------
template<int WSHIFT>
__global__ __launch_bounds__(256) void conv_igemm(
    const float* __restrict__ in, const float* __restrict__ wgt,
    float* __restrict__ part, int Hin, int Win, int Nsp, int K, int kchunk)
{
  __shared__ float As[16][66];
  __shared__ float Bs[16][66];
  int tid = threadIdx.x;
  int tx = tid % 16, ty = tid / 16;
  int m0 = blockIdx.y * 64, n0 = blockIdx.x * 64;
  int kc = blockIdx.z;
  int kt0 = kc * kchunk, kt1 = kt0 + kchunk;
  float acc[4][4] = {};
  for (int kt = kt0; kt < kt1; kt += 16) {
    // A: weights, rows m0..m0+63, cols kt..kt+15
#pragma unroll
    for (int i = 0; i < 4; ++i) {
      int flat = tid + 256 * i;
      int mm = flat >> 4, kk = flat & 15;
      As[kk][mm] = wgt[(size_t)(m0 + mm) * K + kt + kk];
    }
    // B: im2col, rows kt..kt+15, cols n0..n0+63 (consecutive tid -> consec n)
#pragma unroll
    for (int i = 0; i < 4; ++i) {
      int flat = tid + 256 * i;
      int nn = flat & 63, kk = flat >> 6;
      int kabs = kt + kk;
      int ci = kabs / 9, r = kabs % 9;
      int kh = r / 3, kw = r % 3;
      int nabs = n0 + nn;
      int oh = nabs >> WSHIFT, ow = nabs & ((1 << WSHIFT) - 1);
      int iy = oh * 2 + kh, ix = ow * 2 + kw;
      float v = 0.0f;
      if (iy < Hin && ix < Win)
        v = in[((size_t)ci * Hin + iy) * Win + ix];
      Bs[kk][nn] = v;
    }
    __syncthreads();
#pragma unroll
    for (int kk = 0; kk < 16; ++kk) {
      float av[4], bv[4];
#pragma unroll
      for (int i = 0; i < 4; ++i) av[i] = As[kk][ty * 4 + i];
#pragma unroll
      for (int j = 0; j < 4; ++j) bv[j] = Bs[kk][tx * 4 + j];
#pragma unroll
      for (int i = 0; i < 4; ++i)
#pragma unroll
        for (int j = 0; j < 4; ++j)
          acc[i][j] = fmaf(av[i], bv[j], acc[i][j]);
    }
    __syncthreads();
  }
  float* pslab = part + (size_t)blockIdx.z * gridDim.y * 64 * Nsp;
#pragma unroll
  for (int i = 0; i < 4; ++i) {
    int m = m0 + ty * 4 + i;
#pragma unroll
    for (int j = 0; j < 4; ++j) {
      int n = n0 + tx * 4 + j;
      pslab[(size_t)m * Nsp + n] = acc[i][j];
    }
  }
}

// ---------------- reduce conv partials + bias (per-co) + relu --------------
__global__ __launch_bounds__(256) void reduce_conv(
    const float* __restrict__ part, int nchunk,
    const float* __restrict__ bias, float* __restrict__ C,
    int MN, int NSHIFT)
{
  int idx = blockIdx.x * 256 + threadIdx.x;
  if (idx >= MN) return;
  float v = bias[idx >> NSHIFT];
  for (int c = 0; c < nchunk; ++c) v += part[(size_t)c * MN + idx];
  C[idx] = fmaxf(v, 0.0f);
}

// ---------------- maxpool 3x3 s2 SAME: 64x256x256 -> 64x128x128 ------------
__global__ __launch_bounds__(256) void maxpool_kernel(
    const float* __restrict__ in, float* __restrict__ out)
{
  int c = blockIdx.z;
  int w = blockIdx.x * 16 + threadIdx.x;
  int h = blockIdx.y * 16 + threadIdx.y;
  if (w >= 128 || h >= 128) return;
  const float* p = in + (size_t)c * 256 * 256;
  float m = -INFINITY;
  for (int kh = 0; kh < 3; ++kh) {
    int hi = h * 2 + kh;
    if (hi < 256)
      for (int kw = 0; kw < 3; ++kw) {
        int wi = w * 2 + kw;
        if (wi < 256) m = fmaxf(m, p[hi * 256 + wi]);
      }
  }
  out[((size_t)c * 128 + h) * 128 + w] = m;
}

// ---------------- RPN head: cls/reg 1x1 conv + anchor decode ---------------
__global__ __launch_bounds__(256) void rpn_head_kernel(
    const float* __restrict__ t,
    const float* __restrict__ clsw, const float* __restrict__ clsb,
    const float* __restrict__ regw, const float* __restrict__ regb,
    float* __restrict__ scores, float* __restrict__ boxes,
    int H, int W, int stride, float asize, int base)
{
  int idx = blockIdx.x * blockDim.x + threadIdx.x;
  int n = H * W * 3;
  if (idx >= n) return;
  int a = idx % 3;
  int pos = idx / 3;
  int wp = pos % W, hp = pos / W;
  size_t hw = (size_t)H * W;
  const float* tp = t + (size_t)hp * W + wp;
  const float* cw = clsw + a * 256;
  const float* rw0 = regw + (a * 4 + 0) * 256;
  const float* rw1 = regw + (a * 4 + 1) * 256;
  const float* rw2 = regw + (a * 4 + 2) * 256;
  const float* rw3 = regw + (a * 4 + 3) * 256;
  float s = clsb[a];
  float d0 = regb[a * 4 + 0], d1 = regb[a * 4 + 1];
  float d2 = regb[a * 4 + 2], d3 = regb[a * 4 + 3];
  for (int c = 0; c < 256; ++c) {
    float v = tp[c * hw];
    s = fmaf(v, cw[c], s);
    d0 = fmaf(v, rw0[c], d0);
    d1 = fmaf(v, rw1[c], d1);
    d2 = fmaf(v, rw2[c], d2);
    d3 = fmaf(v, rw3[c], d3);
  }
  float r = (a == 0) ? 0.5f : ((a == 1) ? 1.0f : 2.0f);
  float hr = sqrtf(r);
  float ws = asize / hr, hs = asize * hr;
  float cx0 = ((float)wp + 0.5f) * (float)stride;
  float cy0 = ((float)hp + 0.5f) * (float)stride;
  float ax1 = cx0 - ws * 0.5f, ax2 = cx0 + ws * 0.5f;
  float ay1 = cy0 - hs * 0.5f, ay2 = cy0 + hs * 0.5f;
  float aw = ax2 - ax1, ah = ay2 - ay1;
  float acx = ax1 + aw * 0.5f, acy = ay1 + ah * 0.5f;
  float dw = fminf(fmaxf(d2, -4.135f), 4.135f);
  float dh = fminf(fmaxf(d3, -4.135f), 4.135f);
  float cx = d0 * aw + acx;
  float cy = d1 * ah + acy;
  float bw = aw * expf(dw);
  float bh = ah * expf(dh);
  float x1 = fminf(fmaxf(cx - bw * 0.5f, 0.0f), 512.0f);
  float y1 = fminf(fmaxf(cy - bh * 0.5f, 0.0f), 512.0f);
  float x2 = fminf(fmaxf(cx + bw * 0.5f, 0.0f), 512.0f);
  float y2 = fminf(fmaxf(cy + bh * 0.5f, 0.0f), 512.0f);
  scores[base + idx] = s;
  float* bp = boxes + 4 * (size_t)(base + idx);
  bp[0] = x1; bp[1] = y1; bp[2] = x2; bp[3] = y2;
}

// ---------------- per-level exact top-k via radix select -------------------
__global__ __launch_bounds__(256) void topk_kernel(
    const float* __restrict__ scores_all, const float* __restrict__ boxes_all,
    float* __restrict__ sel_s, float* __restrict__ sel_b)
{
  const int offs[5] = {0, 49152, 61440, 64512, 65280};
  const int kks[4]  = {1000, 1000, 1000, 768};
  const int soff[4] = {0, 1000, 2000, 3000};
  int l = blockIdx.x;
  int lo = offs[l], n = offs[l + 1] - lo, k = kks[l], so = soff[l];
  int tid = threadIdx.x;

  if (k >= n) {
    for (int i = tid; i < n; i += blockDim.x) {
      sel_s[so + i] = scores_all[lo + i];
      const float* bp = boxes_all + 4 * (size_t)(lo + i);
      float* op = sel_b + 4 * (size_t)(so + i);
      op[0] = bp[0]; op[1] = bp[1]; op[2] = bp[2]; op[3] = bp[3];
    }
    return;
  }

  __shared__ unsigned hist[256];
  __shared__ unsigned sh_prefix, sh_mask;
  __shared__ int sh_k, cnt1, cnt2;
  if (tid == 0) { sh_prefix = 0u; sh_mask = 0u; sh_k = k; cnt1 = 0; cnt2 = 0; }
  __syncthreads();

  for (int p = 3; p >= 0; --p) {
    hist[tid] = 0u;
    __syncthreads();
    unsigned pre = sh_prefix, msk = sh_mask;
    for (int i = tid; i < n; i += blockDim.x) {
      unsigned u = key32(scores_all[lo + i]);
      if ((u & msk) == pre)
        atomicAdd(&hist[(u >> (p * 8)) & 255u], 1u);
    }
    __syncthreads();
    if (tid == 0) {
      int rem = sh_k, b;
      for (b = 255; b >= 0; --b) {
        int c = (int)hist[b];
        if (rem <= c) break;
        rem -= c;
      }
      if (b < 0) b = 0;
      sh_k = rem;
      sh_prefix |= ((unsigned)b << (p * 8));
      sh_mask |= (255u << (p * 8));
    }
    __syncthreads();
  }
  unsigned T = sh_prefix;

  for (int i = tid; i < n; i += blockDim.x) {
    float sc = scores_all[lo + i];
    if (key32(sc) > T) {
      int pos = atomicAdd(&cnt1, 1);
      sel_s[so + pos] = sc;
      const float* bp = boxes_all + 4 * (size_t)(lo + i);
      float* op = sel_b + 4 * (size_t)(so + pos);
      op[0] = bp[0]; op[1] = bp[1]; op[2] = bp[2]; op[3] = bp[3];
    }
  }
  __syncthreads();
  int ngreater = cnt1;
  for (int i = tid; i < n; i += blockDim.x) {
    float sc = scores_all[lo + i];
    if (key32(sc) == T) {
      int pos = atomicAdd(&cnt2, 1);
      if (ngreater + pos < k) {
        sel_s[so + ngreater + pos] = sc;
        const float* bp = boxes_all + 4 * (size_t)(lo + i);
        float* op = sel_b + 4 * (size_t)(so + ngreater + pos);
        op[0] = bp[0]; op[1] = bp[1]; op[2] = bp[2]; op[3] = bp[3];
      }
    }
  }
}

// ---------------- NMS part (a): parallel IoU suppression bitmask -----------
__global__ __launch_bounds__(256) void nms_mask_kernel(
    const float* __restrict__ sel_b, unsigned long long* __restrict__ mask)
{
  int wid = (blockIdx.x * 256 + threadIdx.x) >> 6;
  int lane = threadIdx.x & 63;
  if (wid >= NSEL) return;
  const float* bb = sel_b + 4 * (size_t)wid;
  float bx1 = bb[0], by1 = bb[1], bx2 = bb[2], by2 = bb[3];
  float barea = (bx2 - bx1) * (by2 - by1);
  unsigned long long* row = mask + (size_t)wid * MWORDS;
  for (int w = 0; w < MWORDS; ++w) {
    int j = w * 64 + lane;
    bool sup = false;
    if (j < NSEL) {
      const float* pB = sel_b + 4 * (size_t)j;
      float px1 = pB[0], py1 = pB[1], px2 = pB[2], py2 = pB[3];
      float ix1 = fmaxf(bx1, px1), iy1 = fmaxf(by1, py1);
      float ix2 = fminf(bx2, px2), iy2 = fminf(by2, py2);
      float inter = fmaxf(ix2 - ix1, 0.0f) * fmaxf(iy2 - iy1, 0.0f);
      float areab = (px2 - px1) * (py2 - py1);
      float iou = inter / fmaxf(barea + areab - inter, 1e-6f);
      sup = iou > 0.7f;
    }
    unsigned long long bal = __ballot(sup);
    if (lane == 0) row[w] = bal;
  }
}

// ---------------- NMS part (b): sequential argmax + mask suppress ----------
__global__ __launch_bounds__(512) void nms_seq_kernel(
    const float* __restrict__ sel_s, const float* __restrict__ sel_b,
    const unsigned long long* __restrict__ mask, float* __restrict__ props)
{
  __shared__ float s[NSEL];
  __shared__ float wv[8];
  __shared__ int wi[8];
  __shared__ int cur;
  int tid = threadIdx.x;
  for (int i = tid; i < NSEL; i += 512) s[i] = sel_s[i];
  __syncthreads();

  for (int it = 0; it < 300; ++it) {
    float bv = -INFINITY;
    int bi = 0x7fffffff;
#pragma unroll
    for (int k = 0; k < 8; ++k) {
      int e = tid + k * 512;
      if (e < NSEL) {
        float v = s[e];
        if (v > bv || (v == bv && e < bi)) { bv = v; bi = e; }
      }
    }
    for (int off = 32; off >= 1; off >>= 1) {
      float ov = __shfl_down(bv, off);
      int oi = __shfl_down(bi, off);
      if (ov > bv || (ov == bv && oi < bi)) { bv = ov; bi = oi; }
    }
    int wave = tid >> 6;
    if ((tid & 63) == 0) { wv[wave] = bv; wi[wave] = bi; }
    __syncthreads();
    if (tid == 0) {
      float v0 = wv[0]; int i0 = wi[0];
      for (int q = 1; q < 8; ++q)
        if (wv[q] > v0 || (wv[q] == v0 && wi[q] < i0)) { v0 = wv[q]; i0 = wi[q]; }
      cur = i0;
    }
    __syncthreads();
    int c = cur;
    if (tid < 4) props[it * 4 + tid] = sel_b[4 * (size_t)c + tid];
    const unsigned long long* row = mask + (size_t)c * MWORDS;
#pragma unroll
    for (int k = 0; k < 8; ++k) {
      int e = tid + k * 512;
      if (e < NSEL) {
        if ((row[e >> 6] >> (e & 63)) & 1ull) s[e] = -INFINITY;
      }
    }
    __syncthreads();
  }
}

// ---------------- RoI align 7x7 (sr=2), writes FC input rows ---------------
__global__ __launch_bounds__(256) void roi_align_kernel(
    const float* __restrict__ props,
    const float* __restrict__ f2, const float* __restrict__ f3,
    const float* __restrict__ f4, const float* __restrict__ f5,
    float* __restrict__ fcin)
{
  int r = blockIdx.x;
  const float* bp = props + 4 * (size_t)r;
  float x1 = bp[0], y1 = bp[1], x2 = bp[2], y2 = bp[3];
  float area = fmaxf((x2 - x1) * (y2 - y1), 1e-6f);
  float lf = floorf(4.0f + log2f(sqrtf(area) / 224.0f));
  lf = fminf(fmaxf(lf, 2.0f), 5.0f);
  int lvl = (int)lf - 2;
  const float* feat; int H; float scale;
  if (lvl == 0)      { feat = f2; H = 128; scale = 0.25f; }
  else if (lvl == 1) { feat = f3; H = 64;  scale = 0.125f; }
  else if (lvl == 2) { feat = f4; H = 32;  scale = 0.0625f; }
  else               { feat = f5; H = 16;  scale = 0.03125f; }
  int W = H;

  __shared__ int   sy0[14], sy1[14], sx0[14], sx1[14];
  __shared__ float swy0[14], swy1[14], swx0[14], swx1[14];
  int tid = threadIdx.x;
  if (tid < 28) {
    int j = tid % 14;
    bool isx = tid >= 14;
    float b1 = (isx ? x1 : y1) * scale;
    float b2 = (isx ? x2 : y2) * scale;
    float bs = fmaxf(b2 - b1, 1.0f) * (1.0f / 7.0f);
    float g = (float)(j >> 1) + ((j & 1) ? 0.75f : 0.25f);
    float coord = b1 + g * bs;
    coord = fminf(fmaxf(coord, 0.0f), (float)(H - 1));
    int c0 = (int)floorf(coord);
    int c1 = min(c0 + 1, H - 1);
    float w1 = coord - (float)c0;
    if (isx) { sx0[j] = c0; sx1[j] = c1; swx1[j] = w1; swx0[j] = 1.0f - w1; }
    else     { sy0[j] = c0; sy1[j] = c1; swy1[j] = w1; swy0[j] = 1.0f - w1; }
  }
  __syncthreads();

  int c = tid;
  const float* fp = feat + (size_t)c * H * W;
  float* op = fcin + (size_t)r * 12544 + (size_t)c * 49;
  for (int oh = 0; oh < 7; ++oh) {
    for (int ow = 0; ow < 7; ++ow) {
      float acc = 0.0f;
#pragma unroll
      for (int sy = 0; sy < 2; ++sy) {
        int i = oh * 2 + sy;
        int yy0 = sy0[i], yy1 = sy1[i];
        float wy0 = swy0[i], wy1 = swy1[i];
#pragma unroll
        for (int sx = 0; sx < 2; ++sx) {
          int j = ow * 2 + sx;
          int xx0 = sx0[j], xx1 = sx1[j];
          float wx0 = swx0[j], wx1 = swx1[j];
          float v = wy0 * wx0 * fp[yy0 * W + xx0]
                  + wy0 * wx1 * fp[yy0 * W + xx1]
                  + wy1 * wx0 * fp[yy1 * W + xx0]
                  + wy1 * wx1 * fp[yy1 * W + xx1];
          acc += v;
        }
      }
      op[oh * 7 + ow] = acc * 0.25f;
    }
  }
}

// ---------------- split-K GEMM: part[kc] += A[M,K] * B[N,K]^T --------------
__global__ __launch_bounds__(256) void gemm_splitk(
    const float* __restrict__ A, const float* __restrict__ B,
    float* __restrict__ part, int M, int N, int K, int klen)
{
  __shared__ float As[16][66];
  __shared__ float Bs[16][66];
  int tid = threadIdx.x;
  int tx = tid % 16, ty = tid / 16;
  int m0 = blockIdx.y * 64, n0 = blockIdx.x * 64;
  int kc = blockIdx.z;
  int kt0 = kc * klen, kt1 = kt0 + klen;
  float acc[4][4] = {};
  for (int kt = kt0; kt < kt1; kt += 16) {
#pragma unroll
    for (int i = 0; i < 4; ++i) {
      int flat = tid + 256 * i;
      int mm = flat >> 4, kk = flat & 15;
      int m = m0 + mm;
      As[kk][mm] = (m < M) ? A[(size_t)m * K + kt + kk] : 0.0f;
      int nn = n0 + mm;
      Bs[kk][mm] = (nn < N) ? B[(size_t)nn * K + kt + kk] : 0.0f;
    }
    __syncthreads();
#pragma unroll
    for (int kk = 0; kk < 16; ++kk) {
      float av[4], bv[4];
#pragma unroll
      for (int i = 0; i < 4; ++i) av[i] = As[kk][ty * 4 + i];
#pragma unroll
      for (int j = 0; j < 4; ++j) bv[j] = Bs[kk][tx * 4 + j];
#pragma unroll
      for (int i = 0; i < 4; ++i)
#pragma unroll
        for (int j = 0; j < 4; ++j)
          acc[i][j] = fmaf(av[i], bv[j], acc[i][j]);
    }
    __syncthreads();
  }
  float* pslab = part + (size_t)kc * M * N;
#pragma unroll
  for (int i = 0; i < 4; ++i) {
    int m = m0 + ty * 4 + i;
    if (m >= M) continue;
#pragma unroll
    for (int j = 0; j < 4; ++j) {
      int n = n0 + tx * 4 + j;
      if (n >= N) continue;
      pslab[(size_t)m * N + n] = acc[i][j];
    }
  }
}

// ---------------- reduce partials + bias + relu (bias along N) -------------
__global__ __launch_bounds__(256) void reduce_bias_relu(
    const float* __restrict__ part, int nchunk,
    const float* __restrict__ bias, float* __restrict__ C,
    int MN, int N, int do_relu)
{
  int idx = blockIdx.x * 256 + threadIdx.x;
  if (idx >= MN) return;
  float v = bias[idx % N];
  for (int c = 0; c < nchunk; ++c) v += part[(size_t)c * MN + idx];
  if (do_relu) v = fmaxf(v, 0.0f);
  C[idx] = v;
}

// ---------------- cls/reg heads: out[300][60] ------------------------------
__global__ __launch_bounds__(256) void heads_kernel(
    const float* __restrict__ h,
    const float* __restrict__ clsw, const float* __restrict__ clsb,
    const float* __restrict__ regw, const float* __restrict__ regb,
    float* __restrict__ out)
{
  int idx = blockIdx.x * blockDim.x + threadIdx.x;
  if (idx >= 300 * 60) return;
  int r = idx / 60, o = idx % 60;
  const float* wrow = (o < 12) ? (clsw + (size_t)o * 1024)
                               : (regw + (size_t)(o - 12) * 1024);
  float acc = (o < 12) ? clsb[o] : regb[o - 12];
  const float* hr = h + (size_t)r * 1024;
  for (int k = 0; k < 1024; ++k) acc = fmaf(hr[k], wrow[k], acc);
  out[idx] = acc;
}

// ---------------------------------------------------------------------------
extern "C" void kernel_launch(void* const* d_in, const int* in_sizes, int n_in,
                              void* d_out, int out_size, void* d_ws, size_t ws_size,
                              hipStream_t stream) {
  const float* images  = (const float*)d_in[0];
  const float* stem_w  = (const float*)d_in[1];
  const float* stem_b  = (const float*)d_in[2];
  const float* c2_w    = (const float*)d_in[3];
  const float* c2_b    = (const float*)d_in[4];
  const float* c3_w    = (const float*)d_in[5];
  const float* c3_b    = (const float*)d_in[6];
  const float* c4_w    = (const float*)d_in[7];
  const float* c4_b    = (const float*)d_in[8];
  const float* c5_w    = (const float*)d_in[9];
  const float* c5_b    = (const float*)d_in[10];
  const float* lat2_w  = (const float*)d_in[11];
  const float* lat2_b  = (const float*)d_in[12];
  const float* lat3_w  = (const float*)d_in[13];
  const float* lat3_b  = (const float*)d_in[14];
  const float* lat4_w  = (const float*)d_in[15];
  const float* lat4_b  = (const float*)d_in[16];
  const float* lat5_w  = (const float*)d_in[17];
  const float* lat5_b  = (const float*)d_in[18];
  const float* fpn2_w  = (const float*)d_in[19];
  const float* fpn2_b  = (const float*)d_in[20];
  const float* fpn3_w  = (const float*)d_in[21];
  const float* fpn3_b  = (const float*)d_in[22];
  const float* fpn4_w  = (const float*)d_in[23];
  const float* fpn4_b  = (const float*)d_in[24];
  const float* fpn5_w  = (const float*)d_in[25];
  const float* fpn5_b  = (const float*)d_in[26];
  const float* rpn_w   = (const float*)d_in[27];
  const float* rpn_b   = (const float*)d_in[28];
  const float* rpncls_w = (const float*)d_in[29];
  const float* rpncls_b = (const float*)d_in[30];
  const float* rpnreg_w = (const float*)d_in[31];
  const float* rpnreg_b = (const float*)d_in[32];
  const float* fc1_w   = (const float*)d_in[33];
  const float* fc1_b   = (const float*)d_in[34];
  const float* fc2_w   = (const float*)d_in[35];
  const float* fc2_b   = (const float*)d_in[36];
  const float* cls_w   = (const float*)d_in[37];
  const float* cls_b   = (const float*)d_in[38];
  const float* reg_w   = (const float*)d_in[39];
  const float* reg_b   = (const float*)d_in[40];

  const size_t NEED = 18677760ull * 4ull;
  if (ws_size < NEED) return;
  float* ws = (float*)d_ws;
  float* STEM = ws;                       // 4,194,304  (later: FCIN 3,763,200)
  float* POOL = ws + 4194304;             // 1,048,576  (later: small buffers)
  float* C2   = ws + 5242880;             // 4,194,304  (later: fpn p2; then fc1 partials)
  float* C3   = ws + 9437184;             // 2,097,152  (later: fpn p3; then fc2 partials)
  float* C4   = ws + 11534336;            // 1,048,576  (later: fpn p4)
  float* C5   = ws + 12582912;            //   524,288  (later: fpn p5)
  float* LAT2 = ws + 13107200;            // 4,194,304  (conv partials; lat2; RPN t; NMS masks)
  float* LAT3 = ws + 17301504;            // 1,048,576
  float* LAT4 = ws + 18350080;            //   262,144
  float* LAT5 = ws + 18612224;            //    65,536
  float* SCORES = POOL;                   // 65,280
  float* BOXES  = POOL + 65280;           // 261,120
  float* SELS   = POOL + 326400;          // 3,768
  float* SELB   = POOL + 330168;          // 15,072
  float* PROPS  = POOL + 345240;          // 1,200
  float* FC1O   = POOL + 346440;          // 307,200
  float* FC2O   = POOL + 653640;          // 307,200
  float* FCIN = STEM;
  float* RPNT = LAT2;
  float* CPART = LAT2;                    // conv split-K partials (4,194,304 each use)
  float* PART1 = C2;                      // 8*300*1024 = 2,457,600 <= 4,194,304
  float* PART2 = C3;                      // 4*300*1024 = 1,228,800 <= 2,097,152
  unsigned long long* MASKS = (unsigned long long*)RPNT;

  dim3 b16(16, 16);

  // backbone
  conv_tile<7,2,16,4,3,2,4><<<dim3(1024, 1), 256, 0, stream>>>(
      images, stem_w, stem_b, STEM, 3, 512, 512, 256, 256, 1, nullptr);
  maxpool_kernel<<<dim3(8, 8, 64), b16, 0, stream>>>(STEM, POOL);
  conv_tile<3,1,64,1,8,1,4><<<dim3(256, 4), 256, 0, stream>>>(
      POOL, c2_w, c2_b, C2, 64, 128, 128, 128, 128, 1, nullptr);

  // deep stride-2 convs as implicit GEMM + split-K (partials in dead LAT2)
  // c3: M=512 N=4096 K=2304, split 2
  conv_igemm<6><<<dim3(64, 8, 2), 256, 0, stream>>>(
      C2, c3_w, CPART, 128, 128, 4096, 2304, 1152);
  reduce_conv<<<(2097152 + 255) / 256, 256, 0, stream>>>(
      CPART, 2, c3_b, C3, 2097152, 12);
  // c4: M=1024 N=1024 K=4608, split 4
  conv_igemm<5><<<dim3(16, 16, 4), 256, 0, stream>>>(
      C3, c4_w, CPART, 64, 64, 1024, 4608, 1152);
  reduce_conv<<<(1048576 + 255) / 256, 256, 0, stream>>>(
      CPART, 4, c4_b, C4, 1048576, 10);
  // c5: M=2048 N=256 K=9216, split 8
  conv_igemm<4><<<dim3(4, 32, 8), 256, 0, stream>>>(
      C4, c5_w, CPART, 32, 32, 256, 9216, 1152);
  reduce_conv<<<(524288 + 255) / 256, 256, 0, stream>>>(
      CPART, 8, c5_b, C5, 524288, 8);

  // FPN laterals (1x1, top-down with fused up2 add)
  conv_tile<1,1,16,4,8,0,4><<<dim3(4, 4), 256, 0, stream>>>(
      C5, lat5_w, lat5_b, LAT5, 2048, 16, 16, 16, 16, 0, nullptr);
  conv_tile<1,1,32,2,8,0,4><<<dim3(16, 4), 256, 0, stream>>>(
      C4, lat4_w, lat4_b, LAT4, 1024, 32, 32, 32, 32, 0, LAT5);
  conv_tile<1,1,64,1,8,0,4><<<dim3(64, 4), 256, 0, stream>>>(
      C3, lat3_w, lat3_b, LAT3, 512, 64, 64, 64, 64, 0, LAT4);
  conv_tile<1,1,64,1,8,0,4><<<dim3(256, 4), 256, 0, stream>>>(
      C2, lat2_w, lat2_b, LAT2, 256, 128, 128, 128, 128, 0, LAT3);

  // FPN 3x3 smoothing (outputs overwrite dead C2..C5)
  conv_tile<3,1,64,1,8,1,4><<<dim3(256, 4), 256, 0, stream>>>(
      LAT2, fpn2_w, fpn2_b, C2, 256, 128, 128, 128, 128, 0, nullptr);
  conv_tile<3,1,64,1,8,1,4><<<dim3(64, 4), 256, 0, stream>>>(
      LAT3, fpn3_w, fpn3_b, C3, 256, 64, 64, 64, 64, 0, nullptr);
  conv_tile<3,1,32,2,8,1,4><<<dim3(16, 4), 256, 0, stream>>>(
      LAT4, fpn4_w, fpn4_b, C4, 256, 32, 32, 32, 32, 0, nullptr);
  conv_tile<3,1,16,4,8,1,4><<<dim3(4, 4), 256, 0, stream>>>(
      LAT5, fpn5_w, fpn5_b, C5, 256, 16, 16, 16, 16, 0, nullptr);

  // RPN per level
  conv_tile<3,1,64,1,8,1,4><<<dim3(256, 4), 256, 0, stream>>>(
      C2, rpn_w, rpn_b, RPNT, 256, 128, 128, 128, 128, 1, nullptr);
  rpn_head_kernel<<<(49152 + 255) / 256, 256, 0, stream>>>(
      RPNT, rpncls_w, rpncls_b, rpnreg_w, rpnreg_b, SCORES, BOXES,
      128, 128, 4, 32.0f, 0);
  conv_tile<3,1,64,1,8,1,4><<<dim3(64, 4), 256, 0, stream>>>(
      C3, rpn_w, rpn_b, RPNT, 256, 64, 64, 64, 64, 1, nullptr);
  rpn_head_kernel<<<(12288 + 255) / 256, 256, 0, stream>>>(
      RPNT, rpncls_w, rpncls_b, rpnreg_w, rpnreg_b, SCORES, BOXES,
      64, 64, 8, 64.0f, 49152);
  conv_tile<3,1,32,2,8,1,4><<<dim3(16, 4), 256, 0, stream>>>(
      C4, rpn_w, rpn_b, RPNT, 256, 32, 32, 32, 32, 1, nullptr);
  rpn_head_kernel<<<(3072 + 255) / 256, 256, 0, stream>>>(
      RPNT, rpncls_w, rpncls_b, rpnreg_w, rpnreg_b, SCORES, BOXES,
      32, 32, 16, 128.0f, 61440);
  conv_tile<3,1,16,4,8,1,4><<<dim3(4, 4), 256, 0, stream>>>(
      C5, rpn_w, rpn_b, RPNT, 256, 16, 16, 16, 16, 1, nullptr);
  rpn_head_kernel<<<(768 + 255) / 256, 256, 0, stream>>>(
      RPNT, rpncls_w, rpncls_b, rpnreg_w, rpnreg_b, SCORES, BOXES,
      16, 16, 32, 256.0f, 64512);

  // selection: top-k -> parallel IoU masks -> lean sequential NMS
  topk_kernel<<<4, 256, 0, stream>>>(SCORES, BOXES, SELS, SELB);
  nms_mask_kernel<<<(NSEL * 64 + 255) / 256, 256, 0, stream>>>(SELB, MASKS);
  nms_seq_kernel<<<1, 512, 0, stream>>>(SELS, SELB, MASKS, PROPS);

  // RoI align into FC input rows (FCIN aliases dead STEM)
  roi_align_kernel<<<300, 256, 0, stream>>>(PROPS, C2, C3, C4, C5, FCIN);

  // FC head, split-K (PART1/PART2 alias C2/C3 which are dead after roi_align)
  gemm_splitk<<<dim3(16, 5, 8), 256, 0, stream>>>(
      FCIN, fc1_w, PART1, 300, 1024, 12544, 1568);
  reduce_bias_relu<<<(307200 + 255) / 256, 256, 0, stream>>>(
      PART1, 8, fc1_b, FC1O, 307200, 1024, 1);
  gemm_splitk<<<dim3(16, 5, 4), 256, 0, stream>>>(
      FC1O, fc2_w, PART2, 300, 1024, 1024, 256);
  reduce_bias_relu<<<(307200 + 255) / 256, 256, 0, stream>>>(
      PART2, 4, fc2_b, FC2O, 307200, 1024, 1);
  heads_kernel<<<(18000 + 255) / 256, 256, 0, stream>>>(
      FC2O, cls_w, cls_b, reg_w, reg_b, (float*)d_out);
}